// Round 3
// baseline (2284.570 us; speedup 1.0000x reference)
//
#include <hip/hip_runtime.h>

#define BLK 128
#define NLEV 16
#define SROW 35   // 32 hash feats + x,y,z staged per point

typedef float f4 __attribute__((ext_vector_type(4)));

__global__ __launch_bounds__(BLK)
void henc_kernel(const float* __restrict__ xs, const float* __restrict__ table,
                 float* __restrict__ out, int n)
{
    __shared__ float sbuf[BLK * SROW];
    // cumulative level offsets (rows of float2) -- from reference OFFSETS
    constexpr int kOff[NLEV] = {0, 4913, 40850, 315475, 839763, 1364051, 1888339,
                                2412627, 2936915, 3461203, 3985491, 4509779,
                                5034067, 5558355, 6082643, 6606931};
    const int tid  = threadIdx.x;
    const int base = blockIdx.x * BLK;
    const int pi   = base + tid;

    float px = 0.f, py = 0.f, pz = 0.f;
    if (pi < n) {
        px = xs[3 * pi + 0];
        py = xs[3 * pi + 1];
        pz = xs[3 * pi + 2];
    }

    float* srow = sbuf + tid * SROW;
    const float2* __restrict__ tab = (const float2*)table;

    #pragma unroll
    for (int l = 0; l < NLEV; ++l) {
        const int res = 16 << l;                    // floor(16 * 2^l)
        const float2* __restrict__ tl = tab + kOff[l];
        const float fres = (float)res;

        float posx = px * fres, posy = py * fres, posz = pz * fres;
        float fxf = floorf(posx), fyf = floorf(posy), fzf = floorf(posz);
        float rx = posx - fxf, ry = posy - fyf, rz = posz - fzf;
        int ix = (int)fxf, iy = (int)fyf, iz = (int)fzf;

        int x0 = min(max(ix, 0), res), x1 = min(ix + 1, res);
        int y0 = min(max(iy, 0), res), y1 = min(iy + 1, res);
        int z0 = min(max(iz, 0), res), z1 = min(iz + 1, res);

        unsigned i000, i001, i010, i011, i100, i101, i110, i111;
        if (l < 3) {
            // dense stride indexing: idx = cx + cy*(res+1) + cz*(res+1)^2
            const unsigned r1 = (unsigned)(res + 1);
            const unsigned r2 = r1 * r1;
            unsigned ax0 = (unsigned)x0, ax1 = (unsigned)x1;
            unsigned by0 = (unsigned)y0 * r1, by1 = (unsigned)y1 * r1;
            unsigned cz0 = (unsigned)z0 * r2, cz1 = (unsigned)z1 * r2;
            i000 = ax0 + by0 + cz0; i001 = ax0 + by0 + cz1;
            i010 = ax0 + by1 + cz0; i011 = ax0 + by1 + cz1;
            i100 = ax1 + by0 + cz0; i101 = ax1 + by0 + cz1;
            i110 = ax1 + by1 + cz0; i111 = ax1 + by1 + cz1;
        } else {
            // spatial hash: (c0*1 ^ c1*2654435761 ^ c2*805459861) % 2^19
            unsigned ax0 = (unsigned)x0, ax1 = (unsigned)x1;
            unsigned by0 = (unsigned)y0 * 2654435761u, by1 = (unsigned)y1 * 2654435761u;
            unsigned cz0 = (unsigned)z0 * 805459861u,  cz1 = (unsigned)z1 * 805459861u;
            i000 = (ax0 ^ by0 ^ cz0) & 524287u; i001 = (ax0 ^ by0 ^ cz1) & 524287u;
            i010 = (ax0 ^ by1 ^ cz0) & 524287u; i011 = (ax0 ^ by1 ^ cz1) & 524287u;
            i100 = (ax1 ^ by0 ^ cz0) & 524287u; i101 = (ax1 ^ by0 ^ cz1) & 524287u;
            i110 = (ax1 ^ by1 ^ cz0) & 524287u; i111 = (ax1 ^ by1 ^ cz1) & 524287u;
        }

        float2 v000 = tl[i000], v001 = tl[i001], v010 = tl[i010], v011 = tl[i011];
        float2 v100 = tl[i100], v101 = tl[i101], v110 = tl[i110], v111 = tl[i111];

        float wx1 = rx, wx0 = 1.f - rx;
        float wy1 = ry, wy0 = 1.f - ry;
        float wz1 = rz, wz0 = 1.f - rz;

        float f0, f1, w;
        w = wx0 * wy0 * wz0; f0  = w * v000.x; f1  = w * v000.y;
        w = wx0 * wy0 * wz1; f0 += w * v001.x; f1 += w * v001.y;
        w = wx0 * wy1 * wz0; f0 += w * v010.x; f1 += w * v010.y;
        w = wx0 * wy1 * wz1; f0 += w * v011.x; f1 += w * v011.y;
        w = wx1 * wy0 * wz0; f0 += w * v100.x; f1 += w * v100.y;
        w = wx1 * wy0 * wz1; f0 += w * v101.x; f1 += w * v101.y;
        w = wx1 * wy1 * wz0; f0 += w * v110.x; f1 += w * v110.y;
        w = wx1 * wy1 * wz1; f0 += w * v111.x; f1 += w * v111.y;

        srow[2 * l]     = f0;
        srow[2 * l + 1] = f1;
    }

    srow[32] = px; srow[33] = py; srow[34] = pz;

    __syncthreads();

    // coalesced write-out of the block's [BLK,71] tile; sin/cos on the fly.
    // out row layout: [32 hash | x,y,z | per-freq f=0..5: sin(x*2^f)*3, cos(x*2^f)*3]
    const int nvalid = min(BLK, n - base);
    float* obase = out + (size_t)base * 71;
    if (nvalid == BLK) {
        f4* o4 = (f4*)obase;
        #pragma unroll 1
        for (int i = tid; i < (BLK * 71) / 4; i += BLK) {
            const int e = 4 * i;
            f4 v;
            #pragma unroll
            for (int j = 0; j < 4; ++j) {
                const int ee = e + j;
                const int p = ee / 71;
                const int f = ee - p * 71;
                float val;
                if (f < SROW) {
                    val = sbuf[p * SROW + f];           // hash feats or raw xyz
                } else {
                    const int g = f - SROW;
                    const int freq = g / 6;
                    const int r = g - 6 * freq;
                    const int dim = (r < 3) ? r : r - 3;
                    const float a = sbuf[p * SROW + 32 + dim] * (float)(1 << freq);
                    val = (r < 3) ? __sinf(a) : __cosf(a);
                }
                v[j] = val;
            }
            __builtin_nontemporal_store(v, &o4[i]);
        }
    } else {
        #pragma unroll 1
        for (int i = tid; i < nvalid * 71; i += BLK) {
            const int p = i / 71;
            const int f = i - p * 71;
            float val;
            if (f < SROW) {
                val = sbuf[p * SROW + f];
            } else {
                const int g = f - SROW;
                const int freq = g / 6;
                const int r = g - 6 * freq;
                const int dim = (r < 3) ? r : r - 3;
                const float a = sbuf[p * SROW + 32 + dim] * (float)(1 << freq);
                val = (r < 3) ? __sinf(a) : __cosf(a);
            }
            __builtin_nontemporal_store(val, &obase[i]);
        }
    }
}

extern "C" void kernel_launch(void* const* d_in, const int* in_sizes, int n_in,
                              void* d_out, int out_size, void* d_ws, size_t ws_size,
                              hipStream_t stream) {
    const float* xs    = (const float*)d_in[0];
    const float* table = (const float*)d_in[1];
    float* out = (float*)d_out;
    const int n = in_sizes[0] / 3;          // 2,000,000 points
    const int grid = (n + BLK - 1) / BLK;
    hipLaunchKernelGGL(henc_kernel, dim3(grid), dim3(BLK), 0, stream,
                       xs, table, out, n);
}

// Round 4
// 1114.670 us; speedup vs baseline: 2.0495x; 2.0495x over previous
//
#include <hip/hip_runtime.h>

typedef float f4 __attribute__((ext_vector_type(4)));

#define BLK 128
#define NLEV 16
#define NHASH 13   // hashed levels 3..15

// cumulative level offsets (rows of float2) -- from reference OFFSETS
__constant__ int kOff[NLEV] = {0, 4913, 40850, 315475, 839763, 1364051, 1888339,
                               2412627, 2936915, 3461203, 3985491, 4509779,
                               5034067, 5558355, 6082643, 6606931};

// ---------------- per-level pass: one hashed level, table L2-resident ----------------
__global__ __launch_bounds__(256)
void level_kernel(const float* __restrict__ xs, const float2* __restrict__ tl,
                  unsigned* __restrict__ scratch, int n, int res)
{
    const int i = blockIdx.x * 256 + threadIdx.x;
    if (i >= n) return;
    const float px = __builtin_nontemporal_load(&xs[3 * i + 0]);
    const float py = __builtin_nontemporal_load(&xs[3 * i + 1]);
    const float pz = __builtin_nontemporal_load(&xs[3 * i + 2]);

    const float fres = (float)res;
    float posx = px * fres, posy = py * fres, posz = pz * fres;
    float fxf = floorf(posx), fyf = floorf(posy), fzf = floorf(posz);
    float rx = posx - fxf, ry = posy - fyf, rz = posz - fzf;
    int ix = (int)fxf, iy = (int)fyf, iz = (int)fzf;

    unsigned ax0 = (unsigned)min(max(ix, 0), res), ax1 = (unsigned)min(ix + 1, res);
    unsigned y0  = (unsigned)min(max(iy, 0), res), y1  = (unsigned)min(iy + 1, res);
    unsigned z0  = (unsigned)min(max(iz, 0), res), z1  = (unsigned)min(iz + 1, res);

    unsigned by0 = y0 * 2654435761u, by1 = y1 * 2654435761u;
    unsigned cz0 = z0 * 805459861u,  cz1 = z1 * 805459861u;
    unsigned i000 = (ax0 ^ by0 ^ cz0) & 524287u, i001 = (ax0 ^ by0 ^ cz1) & 524287u;
    unsigned i010 = (ax0 ^ by1 ^ cz0) & 524287u, i011 = (ax0 ^ by1 ^ cz1) & 524287u;
    unsigned i100 = (ax1 ^ by0 ^ cz0) & 524287u, i101 = (ax1 ^ by0 ^ cz1) & 524287u;
    unsigned i110 = (ax1 ^ by1 ^ cz0) & 524287u, i111 = (ax1 ^ by1 ^ cz1) & 524287u;

    float2 v000 = tl[i000], v001 = tl[i001], v010 = tl[i010], v011 = tl[i011];
    float2 v100 = tl[i100], v101 = tl[i101], v110 = tl[i110], v111 = tl[i111];

    float wx1 = rx, wx0 = 1.f - rx;
    float wy1 = ry, wy0 = 1.f - ry;
    float wz1 = rz, wz0 = 1.f - rz;

    float f0, f1, w;
    w = wx0 * wy0 * wz0; f0  = w * v000.x; f1  = w * v000.y;
    w = wx0 * wy0 * wz1; f0 += w * v001.x; f1 += w * v001.y;
    w = wx0 * wy1 * wz0; f0 += w * v010.x; f1 += w * v010.y;
    w = wx0 * wy1 * wz1; f0 += w * v011.x; f1 += w * v011.y;
    w = wx1 * wy0 * wz0; f0 += w * v100.x; f1 += w * v100.y;
    w = wx1 * wy0 * wz1; f0 += w * v101.x; f1 += w * v101.y;
    w = wx1 * wy1 * wz0; f0 += w * v110.x; f1 += w * v110.y;
    w = wx1 * wy1 * wz1; f0 += w * v111.x; f1 += w * v111.y;

    // pack as 2x bf16 (RTZ); |feat| <= ~1e-4, so error <= ~4e-7 (threshold 2e-2)
    unsigned packed = (__float_as_uint(f0) >> 16) | (__float_as_uint(f1) & 0xFFFF0000u);
    __builtin_nontemporal_store(packed, &scratch[i]);
}

// ---------------- final pass: dense levels 0-2 + pos-enc + merge + coalesced write ----
__global__ __launch_bounds__(BLK)
void final_kernel(const float* __restrict__ xs, const float* __restrict__ table,
                  const unsigned* __restrict__ scratch, float* __restrict__ out, int n)
{
    __shared__ float sbuf[BLK * 71];
    const int tid  = threadIdx.x;
    const int base = blockIdx.x * BLK;
    const int pi   = base + tid;

    float px = 0.f, py = 0.f, pz = 0.f;
    if (pi < n) {
        px = xs[3 * pi + 0];
        py = xs[3 * pi + 1];
        pz = xs[3 * pi + 2];
    }

    float* srow = sbuf + tid * 71;
    const float2* __restrict__ tab = (const float2*)table;

    // dense levels 0..2 (tables total 2.5 MB -> cache-hot)
    #pragma unroll
    for (int l = 0; l < 3; ++l) {
        const int res = 16 << l;
        const float2* __restrict__ tl = tab + kOff[l];
        const float fres = (float)res;

        float posx = px * fres, posy = py * fres, posz = pz * fres;
        float fxf = floorf(posx), fyf = floorf(posy), fzf = floorf(posz);
        float rx = posx - fxf, ry = posy - fyf, rz = posz - fzf;
        int ix = (int)fxf, iy = (int)fyf, iz = (int)fzf;

        unsigned x0 = (unsigned)min(max(ix, 0), res), x1 = (unsigned)min(ix + 1, res);
        unsigned y0 = (unsigned)min(max(iy, 0), res), y1 = (unsigned)min(iy + 1, res);
        unsigned z0 = (unsigned)min(max(iz, 0), res), z1 = (unsigned)min(iz + 1, res);

        const unsigned r1 = (unsigned)(res + 1);
        const unsigned r2 = r1 * r1;
        unsigned by0 = y0 * r1, by1 = y1 * r1;
        unsigned cz0 = z0 * r2, cz1 = z1 * r2;
        unsigned i000 = x0 + by0 + cz0, i001 = x0 + by0 + cz1;
        unsigned i010 = x0 + by1 + cz0, i011 = x0 + by1 + cz1;
        unsigned i100 = x1 + by0 + cz0, i101 = x1 + by0 + cz1;
        unsigned i110 = x1 + by1 + cz0, i111 = x1 + by1 + cz1;

        float2 v000 = tl[i000], v001 = tl[i001], v010 = tl[i010], v011 = tl[i011];
        float2 v100 = tl[i100], v101 = tl[i101], v110 = tl[i110], v111 = tl[i111];

        float wx1 = rx, wx0 = 1.f - rx;
        float wy1 = ry, wy0 = 1.f - ry;
        float wz1 = rz, wz0 = 1.f - rz;

        float f0, f1, w;
        w = wx0 * wy0 * wz0; f0  = w * v000.x; f1  = w * v000.y;
        w = wx0 * wy0 * wz1; f0 += w * v001.x; f1 += w * v001.y;
        w = wx0 * wy1 * wz0; f0 += w * v010.x; f1 += w * v010.y;
        w = wx0 * wy1 * wz1; f0 += w * v011.x; f1 += w * v011.y;
        w = wx1 * wy0 * wz0; f0 += w * v100.x; f1 += w * v100.y;
        w = wx1 * wy0 * wz1; f0 += w * v101.x; f1 += w * v101.y;
        w = wx1 * wy1 * wz0; f0 += w * v110.x; f1 += w * v110.y;
        w = wx1 * wy1 * wz1; f0 += w * v111.x; f1 += w * v111.y;

        srow[2 * l]     = f0;
        srow[2 * l + 1] = f1;
    }

    // hashed levels 3..15 from scratch (packed bf16 pairs)
    if (pi < n) {
        #pragma unroll
        for (int h = 0; h < NHASH; ++h) {
            unsigned u = __builtin_nontemporal_load(&scratch[(size_t)h * n + pi]);
            srow[6 + 2 * h]     = __uint_as_float(u << 16);
            srow[7 + 2 * h]     = __uint_as_float(u & 0xFFFF0000u);
        }
    }

    // positional encoding: [x,y,z | per-freq f: sin(x,y,z*2^f) then cos(...)]
    srow[32] = px; srow[33] = py; srow[34] = pz;
    float coef = 1.f;
    #pragma unroll
    for (int f = 0; f < 6; ++f) {
        float s, c;
        __sincosf(px * coef, &s, &c); srow[35 + 6*f + 0] = s; srow[35 + 6*f + 3] = c;
        __sincosf(py * coef, &s, &c); srow[35 + 6*f + 1] = s; srow[35 + 6*f + 4] = c;
        __sincosf(pz * coef, &s, &c); srow[35 + 6*f + 2] = s; srow[35 + 6*f + 5] = c;
        coef *= 2.f;
    }

    __syncthreads();

    const int nvalid = min(BLK, n - base);
    float* obase = out + (size_t)base * 71;
    if (nvalid == BLK) {
        f4* o4 = (f4*)obase;
        const f4* s4 = (const f4*)sbuf;
        #pragma unroll 1
        for (int i = tid; i < (BLK * 71) / 4; i += BLK)
            __builtin_nontemporal_store(s4[i], &o4[i]);
    } else {
        #pragma unroll 1
        for (int i = tid; i < nvalid * 71; i += BLK)
            __builtin_nontemporal_store(sbuf[i], &obase[i]);
    }
}

// ---------------- fallback: monolithic (round-3) kernel, used if ws too small --------
__global__ __launch_bounds__(BLK)
void mono_kernel(const float* __restrict__ xs, const float* __restrict__ table,
                 float* __restrict__ out, int n)
{
    __shared__ float sbuf[BLK * 71];
    const int tid  = threadIdx.x;
    const int base = blockIdx.x * BLK;
    const int pi   = base + tid;

    float px = 0.f, py = 0.f, pz = 0.f;
    if (pi < n) {
        px = xs[3 * pi + 0];
        py = xs[3 * pi + 1];
        pz = xs[3 * pi + 2];
    }

    float* srow = sbuf + tid * 71;
    const float2* __restrict__ tab = (const float2*)table;

    #pragma unroll
    for (int l = 0; l < NLEV; ++l) {
        const int res = 16 << l;
        const float2* __restrict__ tl = tab + kOff[l];
        const float fres = (float)res;

        float posx = px * fres, posy = py * fres, posz = pz * fres;
        float fxf = floorf(posx), fyf = floorf(posy), fzf = floorf(posz);
        float rx = posx - fxf, ry = posy - fyf, rz = posz - fzf;
        int ix = (int)fxf, iy = (int)fyf, iz = (int)fzf;

        unsigned x0 = (unsigned)min(max(ix, 0), res), x1 = (unsigned)min(ix + 1, res);
        unsigned y0 = (unsigned)min(max(iy, 0), res), y1 = (unsigned)min(iy + 1, res);
        unsigned z0 = (unsigned)min(max(iz, 0), res), z1 = (unsigned)min(iz + 1, res);

        unsigned i000, i001, i010, i011, i100, i101, i110, i111;
        if (l < 3) {
            const unsigned r1 = (unsigned)(res + 1);
            const unsigned r2 = r1 * r1;
            unsigned by0 = y0 * r1, by1 = y1 * r1;
            unsigned cz0 = z0 * r2, cz1 = z1 * r2;
            i000 = x0 + by0 + cz0; i001 = x0 + by0 + cz1;
            i010 = x0 + by1 + cz0; i011 = x0 + by1 + cz1;
            i100 = x1 + by0 + cz0; i101 = x1 + by0 + cz1;
            i110 = x1 + by1 + cz0; i111 = x1 + by1 + cz1;
        } else {
            unsigned by0 = y0 * 2654435761u, by1 = y1 * 2654435761u;
            unsigned cz0 = z0 * 805459861u,  cz1 = z1 * 805459861u;
            i000 = (x0 ^ by0 ^ cz0) & 524287u; i001 = (x0 ^ by0 ^ cz1) & 524287u;
            i010 = (x0 ^ by1 ^ cz0) & 524287u; i011 = (x0 ^ by1 ^ cz1) & 524287u;
            i100 = (x1 ^ by0 ^ cz0) & 524287u; i101 = (x1 ^ by0 ^ cz1) & 524287u;
            i110 = (x1 ^ by1 ^ cz0) & 524287u; i111 = (x1 ^ by1 ^ cz1) & 524287u;
        }

        float2 v000 = tl[i000], v001 = tl[i001], v010 = tl[i010], v011 = tl[i011];
        float2 v100 = tl[i100], v101 = tl[i101], v110 = tl[i110], v111 = tl[i111];

        float wx1 = rx, wx0 = 1.f - rx;
        float wy1 = ry, wy0 = 1.f - ry;
        float wz1 = rz, wz0 = 1.f - rz;

        float f0, f1, w;
        w = wx0 * wy0 * wz0; f0  = w * v000.x; f1  = w * v000.y;
        w = wx0 * wy0 * wz1; f0 += w * v001.x; f1 += w * v001.y;
        w = wx0 * wy1 * wz0; f0 += w * v010.x; f1 += w * v010.y;
        w = wx0 * wy1 * wz1; f0 += w * v011.x; f1 += w * v011.y;
        w = wx1 * wy0 * wz0; f0 += w * v100.x; f1 += w * v100.y;
        w = wx1 * wy0 * wz1; f0 += w * v101.x; f1 += w * v101.y;
        w = wx1 * wy1 * wz0; f0 += w * v110.x; f1 += w * v110.y;
        w = wx1 * wy1 * wz1; f0 += w * v111.x; f1 += w * v111.y;

        srow[2 * l]     = f0;
        srow[2 * l + 1] = f1;
    }

    srow[32] = px; srow[33] = py; srow[34] = pz;
    float coef = 1.f;
    #pragma unroll
    for (int f = 0; f < 6; ++f) {
        float s, c;
        __sincosf(px * coef, &s, &c); srow[35 + 6*f + 0] = s; srow[35 + 6*f + 3] = c;
        __sincosf(py * coef, &s, &c); srow[35 + 6*f + 1] = s; srow[35 + 6*f + 4] = c;
        __sincosf(pz * coef, &s, &c); srow[35 + 6*f + 2] = s; srow[35 + 6*f + 5] = c;
        coef *= 2.f;
    }

    __syncthreads();

    const int nvalid = min(BLK, n - base);
    float* obase = out + (size_t)base * 71;
    if (nvalid == BLK) {
        f4* o4 = (f4*)obase;
        const f4* s4 = (const f4*)sbuf;
        #pragma unroll 1
        for (int i = tid; i < (BLK * 71) / 4; i += BLK)
            __builtin_nontemporal_store(s4[i], &o4[i]);
    } else {
        #pragma unroll 1
        for (int i = tid; i < nvalid * 71; i += BLK)
            __builtin_nontemporal_store(sbuf[i], &obase[i]);
    }
}

extern "C" void kernel_launch(void* const* d_in, const int* in_sizes, int n_in,
                              void* d_out, int out_size, void* d_ws, size_t ws_size,
                              hipStream_t stream) {
    const float* xs    = (const float*)d_in[0];
    const float* table = (const float*)d_in[1];
    float* out = (float*)d_out;
    const int n = in_sizes[0] / 3;          // 2,000,000 points

    const size_t need = (size_t)NHASH * (size_t)n * 4u;
    if (ws_size >= need) {
        unsigned* scratch = (unsigned*)d_ws;
        const float2* tab = (const float2*)table;
        static const int kOffH[NLEV] = {0, 4913, 40850, 315475, 839763, 1364051, 1888339,
                                        2412627, 2936915, 3461203, 3985491, 4509779,
                                        5034067, 5558355, 6082643, 6606931};
        const int gl = (n + 255) / 256;
        for (int l = 3; l < NLEV; ++l) {
            hipLaunchKernelGGL(level_kernel, dim3(gl), dim3(256), 0, stream,
                               xs, tab + kOffH[l], scratch + (size_t)(l - 3) * n,
                               n, 16 << l);
        }
        const int gf = (n + BLK - 1) / BLK;
        hipLaunchKernelGGL(final_kernel, dim3(gf), dim3(BLK), 0, stream,
                           xs, table, scratch, out, n);
    } else {
        const int grid = (n + BLK - 1) / BLK;
        hipLaunchKernelGGL(mono_kernel, dim3(grid), dim3(BLK), 0, stream,
                           xs, table, out, n);
    }
}

// Round 5
// 881.412 us; speedup vs baseline: 2.5919x; 1.2646x over previous
//
#include <hip/hip_runtime.h>

typedef float f4 __attribute__((ext_vector_type(4)));

#define BLK 128
#define NLEV 16
#define NHASH 13   // hashed levels 3..15

// cumulative level offsets (rows of float2) -- from reference OFFSETS
__constant__ int kOff[NLEV] = {0, 4913, 40850, 315475, 839763, 1364051, 1888339,
                               2412627, 2936915, 3461203, 3985491, 4509779,
                               5034067, 5558355, 6082643, 6606931};

// ---------------- fused hashed-level passes: blockIdx.y = level-3 ----------------
// x-fastest dispatch keeps one level's 4MB table L2-resident at a time.
__global__ __launch_bounds__(256)
void levels_kernel(const float* __restrict__ xs, const float2* __restrict__ tab,
                   unsigned* __restrict__ scratch, int n)
{
    const int lev = blockIdx.y;                   // 0..12 (level 3+lev)
    const int i   = blockIdx.x * 256 + threadIdx.x;
    if (i >= n) return;

    const int res = 16 << (3 + lev);
    const float2* __restrict__ tl = tab + kOff[3 + lev];

    const float px = __builtin_nontemporal_load(&xs[3 * i + 0]);
    const float py = __builtin_nontemporal_load(&xs[3 * i + 1]);
    const float pz = __builtin_nontemporal_load(&xs[3 * i + 2]);

    const float fres = (float)res;
    float posx = px * fres, posy = py * fres, posz = pz * fres;
    float fxf = floorf(posx), fyf = floorf(posy), fzf = floorf(posz);
    float rx = posx - fxf, ry = posy - fyf, rz = posz - fzf;

    // no clamps needed: when floor rounds to res, frac==0 zeroes that corner's weight,
    // and hashed indices are masked so all reads stay in-bounds.
    const unsigned mask = 524287u;
    unsigned hx  = (unsigned)(int)fxf;
    unsigned hy0 = (unsigned)(int)fyf * 2654435761u;
    unsigned hy1 = hy0 + 2654435761u;
    unsigned hz0 = (unsigned)(int)fzf * 805459861u;
    unsigned hz1 = hz0 + 805459861u;
    unsigned h00 = hy0 ^ hz0, h01 = hy0 ^ hz1, h10 = hy1 ^ hz0, h11 = hy1 ^ hz1;

    float2 v000, v001, v010, v011, v100, v101, v110, v111;
    if ((hx & 1u) == 0u) {
        // x0 even: idx(x1) = idx(x0)^1 -> adjacent aligned pair, one dwordx4 each
        #define PAIRH(H, VA, VB) { \
            unsigned ia = (hx ^ (H)) & mask; \
            f4 q = *(const f4*)(tl + (ia & ~1u)); \
            bool sw = (ia & 1u) != 0u; \
            VA.x = sw ? q.z : q.x; VA.y = sw ? q.w : q.y; \
            VB.x = sw ? q.x : q.z; VB.y = sw ? q.y : q.w; }
        PAIRH(h00, v000, v100)
        PAIRH(h01, v001, v101)
        PAIRH(h10, v010, v110)
        PAIRH(h11, v011, v111)
        #undef PAIRH
    } else {
        unsigned hx1 = hx + 1u;
        v000 = tl[(hx ^ h00) & mask]; v100 = tl[(hx1 ^ h00) & mask];
        v001 = tl[(hx ^ h01) & mask]; v101 = tl[(hx1 ^ h01) & mask];
        v010 = tl[(hx ^ h10) & mask]; v110 = tl[(hx1 ^ h10) & mask];
        v011 = tl[(hx ^ h11) & mask]; v111 = tl[(hx1 ^ h11) & mask];
    }

    float wx1 = rx, wx0 = 1.f - rx;
    float wy1 = ry, wy0 = 1.f - ry;
    float wz1 = rz, wz0 = 1.f - rz;

    float f0, f1, w;
    w = wx0 * wy0 * wz0; f0  = w * v000.x; f1  = w * v000.y;
    w = wx0 * wy0 * wz1; f0 += w * v001.x; f1 += w * v001.y;
    w = wx0 * wy1 * wz0; f0 += w * v010.x; f1 += w * v010.y;
    w = wx0 * wy1 * wz1; f0 += w * v011.x; f1 += w * v011.y;
    w = wx1 * wy0 * wz0; f0 += w * v100.x; f1 += w * v100.y;
    w = wx1 * wy0 * wz1; f0 += w * v101.x; f1 += w * v101.y;
    w = wx1 * wy1 * wz0; f0 += w * v110.x; f1 += w * v110.y;
    w = wx1 * wy1 * wz1; f0 += w * v111.x; f1 += w * v111.y;

    // pack as 2x bf16 (RTZ); |feat| <= ~1e-4 -> error ~4e-7 (threshold 2e-2)
    unsigned packed = (__float_as_uint(f0) >> 16) | (__float_as_uint(f1) & 0xFFFF0000u);
    __builtin_nontemporal_store(packed, &scratch[(size_t)lev * n + i]);
}

// ---------------- final pass: dense levels 0-2 + pos-enc + merge + coalesced write ----
__global__ __launch_bounds__(BLK)
void final_kernel(const float* __restrict__ xs, const float* __restrict__ table,
                  const unsigned* __restrict__ scratch, float* __restrict__ out, int n)
{
    __shared__ float sbuf[BLK * 71];
    const int tid  = threadIdx.x;
    const int base = blockIdx.x * BLK;
    const int pi   = base + tid;

    float px = 0.f, py = 0.f, pz = 0.f;
    if (pi < n) {
        px = xs[3 * pi + 0];
        py = xs[3 * pi + 1];
        pz = xs[3 * pi + 2];
    }

    float* srow = sbuf + tid * 71;
    const float2* __restrict__ tab = (const float2*)table;

    // dense levels 0..2 (tables total 2.5 MB -> cache-hot); idx(x1)=idx(x0)+1 always
    #pragma unroll
    for (int l = 0; l < 3; ++l) {
        const int res = 16 << l;
        const float2* __restrict__ tl = tab + kOff[l];
        const float fres = (float)res;

        float posx = px * fres, posy = py * fres, posz = pz * fres;
        float fxf = floorf(posx), fyf = floorf(posy), fzf = floorf(posz);
        float rx = posx - fxf, ry = posy - fyf, rz = posz - fzf;

        const unsigned r1 = (unsigned)(res + 1);
        const unsigned r2 = r1 * r1;
        unsigned x0 = (unsigned)(int)fxf;
        unsigned by0 = (unsigned)(int)fyf * r1; unsigned by1 = by0 + r1;
        unsigned cz0 = (unsigned)(int)fzf * r2; unsigned cz1 = cz0 + r2;

        float2 v000, v001, v010, v011, v100, v101, v110, v111;
        #define PAIRD(B, VA, VB) { \
            unsigned i0 = x0 + (B); \
            if ((i0 & 1u) == 0u) { f4 q = *(const f4*)(tl + i0); \
                VA.x = q.x; VA.y = q.y; VB.x = q.z; VB.y = q.w; } \
            else { VA = tl[i0]; VB = tl[i0 + 1u]; } }
        PAIRD(by0 + cz0, v000, v100)
        PAIRD(by0 + cz1, v001, v101)
        PAIRD(by1 + cz0, v010, v110)
        PAIRD(by1 + cz1, v011, v111)
        #undef PAIRD

        float wx1 = rx, wx0 = 1.f - rx;
        float wy1 = ry, wy0 = 1.f - ry;
        float wz1 = rz, wz0 = 1.f - rz;

        float f0, f1, w;
        w = wx0 * wy0 * wz0; f0  = w * v000.x; f1  = w * v000.y;
        w = wx0 * wy0 * wz1; f0 += w * v001.x; f1 += w * v001.y;
        w = wx0 * wy1 * wz0; f0 += w * v010.x; f1 += w * v010.y;
        w = wx0 * wy1 * wz1; f0 += w * v011.x; f1 += w * v011.y;
        w = wx1 * wy0 * wz0; f0 += w * v100.x; f1 += w * v100.y;
        w = wx1 * wy0 * wz1; f0 += w * v101.x; f1 += w * v101.y;
        w = wx1 * wy1 * wz0; f0 += w * v110.x; f1 += w * v110.y;
        w = wx1 * wy1 * wz1; f0 += w * v111.x; f1 += w * v111.y;

        srow[2 * l]     = f0;
        srow[2 * l + 1] = f1;
    }

    // hashed levels 3..15 from scratch (packed bf16 pairs)
    if (pi < n) {
        #pragma unroll
        for (int h = 0; h < NHASH; ++h) {
            unsigned u = __builtin_nontemporal_load(&scratch[(size_t)h * n + pi]);
            srow[6 + 2 * h] = __uint_as_float(u << 16);
            srow[7 + 2 * h] = __uint_as_float(u & 0xFFFF0000u);
        }
    }

    // positional encoding: [x,y,z | per-freq f: sin(x,y,z*2^f) then cos(...)]
    srow[32] = px; srow[33] = py; srow[34] = pz;
    float coef = 1.f;
    #pragma unroll
    for (int f = 0; f < 6; ++f) {
        float s, c;
        __sincosf(px * coef, &s, &c); srow[35 + 6*f + 0] = s; srow[35 + 6*f + 3] = c;
        __sincosf(py * coef, &s, &c); srow[35 + 6*f + 1] = s; srow[35 + 6*f + 4] = c;
        __sincosf(pz * coef, &s, &c); srow[35 + 6*f + 2] = s; srow[35 + 6*f + 5] = c;
        coef *= 2.f;
    }

    __syncthreads();

    const int nvalid = min(BLK, n - base);
    float* obase = out + (size_t)base * 71;
    if (nvalid == BLK) {
        f4* o4 = (f4*)obase;
        const f4* s4 = (const f4*)sbuf;
        #pragma unroll 1
        for (int i = tid; i < (BLK * 71) / 4; i += BLK)
            __builtin_nontemporal_store(s4[i], &o4[i]);
    } else {
        #pragma unroll 1
        for (int i = tid; i < nvalid * 71; i += BLK)
            __builtin_nontemporal_store(sbuf[i], &obase[i]);
    }
}

extern "C" void kernel_launch(void* const* d_in, const int* in_sizes, int n_in,
                              void* d_out, int out_size, void* d_ws, size_t ws_size,
                              hipStream_t stream) {
    const float* xs    = (const float*)d_in[0];
    const float* table = (const float*)d_in[1];
    float* out = (float*)d_out;
    const int n = in_sizes[0] / 3;          // 2,000,000 points

    unsigned* scratch = (unsigned*)d_ws;    // need 13*n*4 = 104 MB (ws is ~2.3 GB)
    const float2* tab = (const float2*)table;

    const int bpl = (n + 255) / 256;
    hipLaunchKernelGGL(levels_kernel, dim3(bpl, NHASH), dim3(256), 0, stream,
                       xs, tab, scratch, n);

    const int gf = (n + BLK - 1) / BLK;
    hipLaunchKernelGGL(final_kernel, dim3(gf), dim3(BLK), 0, stream,
                       xs, table, scratch, out, n);
}